// Round 7
// baseline (271.472 us; speedup 1.0000x reference)
//
#include <hip/hip_runtime.h>
#include <hip/hip_bf16.h>

#define HW 90000
#define CROP 300
// scale * log2(e) = (1/sqrt(32)) * 1.4426950408889634
#define C2EXP 0.25503492f

typedef __attribute__((ext_vector_type(8))) short s8v;
typedef __attribute__((ext_vector_type(4))) float f4v;
#define MFMA16(a,b,c) __builtin_amdgcn_mfma_f32_16x16x32_bf16(a,b,c,0,0,0)

__device__ __forceinline__ unsigned short f2bf(float f) {
    unsigned int u = __float_as_uint(f);
    return (unsigned short)((u + 0x7fffu + ((u >> 16) & 1u)) >> 16);
}
__device__ __forceinline__ float bf2f(unsigned short s) {
    return __uint_as_float(((unsigned int)s) << 16);
}
// pack two fp32 -> bf16 pair by truncation (1 v_perm): low16=trunc(a), high16=trunc(b)
__device__ __forceinline__ unsigned pk_trunc(float a, float b) {
    return __builtin_amdgcn_perm(__float_as_uint(b), __float_as_uint(a), 0x07060302u);
}
__device__ __forceinline__ unsigned pk_rne(float a, float b) {
    return (unsigned)f2bf(a) | ((unsigned)f2bf(b) << 16);
}

// ---- K0: stage weights bf16 + build Ms = Wq^T @ Wk * scale * log2e (bf16, [e'][e]) ----
__global__ void prep_kernel(const float* __restrict__ w1, const float* __restrict__ wq,
                            const float* __restrict__ wkv, const float* __restrict__ wo,
                            const float* __restrict__ w2,
                            short* __restrict__ w1b, short* __restrict__ wkvb,
                            short* __restrict__ wob, short* __restrict__ w2b,
                            short* __restrict__ msb) {
    int idx = blockIdx.x * blockDim.x + threadIdx.x;
    int stride = gridDim.x * blockDim.x;
    for (int i = idx; i < 16384; i += stride) w1b[i] = (short)f2bf(w1[i]);   // [o][k] 64x256
    for (int i = idx; i < 2048; i += stride)  wkvb[i] = (short)f2bf(wkv[i]); // [o][e] 64x32
    for (int i = idx; i < 4096; i += stride)  wob[i] = (short)f2bf(wo[i]);   // [c][e] 64x64
    for (int i = idx; i < 8192; i += stride)  w2b[i] = (short)f2bf(w2[i]);   // [o][c] 64x128
    for (int i = idx; i < 1024; i += stride) {   // msb[e'][e] = C * sum_a wq[a][e]*wkv_k[a][e']
        int ep = i >> 5, e = i & 31;
        float s = 0.f;
        for (int a = 0; a < 32; ++a) s += wq[a * 32 + e] * wkv[a * 32 + ep];
        msb[i] = (short)f2bf(s * C2EXP);
    }
}

// ---- K1: conv1 via MFMA. Wave = 32 px (2 m-tiles); lane n loads float2 at
// px s0+2n. Pixel map: p = s0 + 2*row + mt. W1 (full 32KB!) staged in LDS. ----
__global__ __launch_bounds__(256, 4) void conv1_mfma(const float* __restrict__ x,
        const short* __restrict__ w1b, short* __restrict__ y1b, float* __restrict__ stat) {
    __shared__ __align__(16) short lw[16384];
    __shared__ float red[2][4][64];
    const int wave = threadIdx.x >> 6, lane = threadIdx.x & 63;
    const int q = lane >> 4, n = lane & 15;
    for (int i = threadIdx.x; i < 2048; i += 256)   // FIX: full 2048 uint4 = 32KB
        ((uint4*)lw)[i] = ((const uint4*)w1b)[i];
    __syncthreads();

    const int s0 = blockIdx.x * 128 + wave * 32;
    int pbx = s0 + 2 * n;
    if (pbx > HW - 2) pbx = HW - 2;
    f4v acc[2][4];
#pragma unroll
    for (int mt = 0; mt < 2; ++mt)
#pragma unroll
        for (int nt = 0; nt < 4; ++nt) acc[mt][nt] = f4v{0.f, 0.f, 0.f, 0.f};

    float2 cur[8], nxt[8];
#pragma unroll
    for (int j = 0; j < 8; ++j)
        cur[j] = *(const float2*)(x + (size_t)(q * 8 + j) * HW + pbx);
#pragma unroll
    for (int kb = 0; kb < 8; ++kb) {
        if (kb < 7) {
#pragma unroll
            for (int j = 0; j < 8; ++j)
                nxt[j] = *(const float2*)(x + (size_t)((kb + 1) * 32 + q * 8 + j) * HW + pbx);
        }
        s8v A[2];
        {
            union { unsigned u[4]; s8v v; } a0, a1;
#pragma unroll
            for (int w = 0; w < 4; ++w) {
                a0.u[w] = pk_trunc(cur[2 * w].x, cur[2 * w + 1].x);
                a1.u[w] = pk_trunc(cur[2 * w].y, cur[2 * w + 1].y);
            }
            A[0] = a0.v; A[1] = a1.v;
        }
#pragma unroll
        for (int nt = 0; nt < 4; ++nt) {
            int c = (nt & 1) + 2 * n + 32 * (nt >> 1);
            s8v B = *(const s8v*)(lw + c * 256 + kb * 32 + q * 8);
            acc[0][nt] = MFMA16(A[0], B, acc[0][nt]);
            acc[1][nt] = MFMA16(A[1], B, acc[1][nt]);
        }
        if (kb < 7) {
#pragma unroll
            for (int j = 0; j < 8; ++j) cur[j] = nxt[j];
        }
    }

    // store bf16 [p][64]: lane n holds channels {2n,2n+1,32+2n,33+2n}; fused stats
    float s1[4] = {0.f, 0.f, 0.f, 0.f}, s2[4] = {0.f, 0.f, 0.f, 0.f};
#pragma unroll
    for (int mt = 0; mt < 2; ++mt)
#pragma unroll
        for (int r = 0; r < 4; ++r) {
            int p = s0 + 2 * (q * 4 + r) + mt;
            if (p < HW) {
                float v0 = acc[mt][0][r], v1 = acc[mt][1][r];
                float v2 = acc[mt][2][r], v3 = acc[mt][3][r];
                *(unsigned*)(y1b + (size_t)p * 64 + 2 * n)      = pk_rne(v0, v1);
                *(unsigned*)(y1b + (size_t)p * 64 + 32 + 2 * n) = pk_rne(v2, v3);
                s1[0] += v0; s2[0] += v0 * v0;
                s1[1] += v1; s2[1] += v1 * v1;
                s1[2] += v2; s2[2] += v2 * v2;
                s1[3] += v3; s2[3] += v3 * v3;
            }
        }
#pragma unroll
    for (int m = 16; m < 64; m <<= 1)
#pragma unroll
        for (int nt = 0; nt < 4; ++nt) {
            s1[nt] += __shfl_xor(s1[nt], m, 64);
            s2[nt] += __shfl_xor(s2[nt], m, 64);
        }
    if (lane < 16)
#pragma unroll
        for (int nt = 0; nt < 4; ++nt) {
            int c = (nt & 1) + 2 * lane + 32 * (nt >> 1);
            red[0][wave][c] = s1[nt];
            red[1][wave][c] = s2[nt];
        }
    __syncthreads();
    if (threadIdx.x < 128) {
        int k = threadIdx.x >> 6, c = threadIdx.x & 63;
        atomicAdd(&stat[k * 64 + c],
                  red[k][0][c] + red[k][1][c] + red[k][2][c] + red[k][3][c]);
    }
}

// ---- BN finalize ----
__global__ void bn_fin_kernel(const float* __restrict__ stat,
        const float* __restrict__ g, const float* __restrict__ b, float* __restrict__ ab) {
    int c = threadIdx.x;
    float m = stat[c] * (1.f / HW);
    float v = stat[64 + c] * (1.f / HW) - m * m;
    float ac = g[c] * rsqrtf(v + 1e-5f);
    ab[c] = ac;
    ab[64 + c] = b[c] - m * ac;
}

// ---- K2: x1b = bf16(relu(BN1(y1b))), 16B per thread ----
__global__ __launch_bounds__(256) void bnrelu_kernel(const short* __restrict__ y1b,
        const float* __restrict__ ab1, short* __restrict__ x1b) {
    int t = blockIdx.x * 256 + threadIdx.x;
    if (t >= 720000) return;
    int cb = 8 * (t & 7);
    float4 a0 = *(const float4*)(ab1 + cb), a1 = *(const float4*)(ab1 + cb + 4);
    float4 b0 = *(const float4*)(ab1 + 64 + cb), b1 = *(const float4*)(ab1 + 64 + cb + 4);
    uint4 u = ((const uint4*)y1b)[t];
    float r0 = fmaxf(fmaf(a0.x, __uint_as_float(u.x << 16), b0.x), 0.f);
    float r1 = fmaxf(fmaf(a0.y, __uint_as_float(u.x & 0xffff0000u), b0.y), 0.f);
    float r2 = fmaxf(fmaf(a0.z, __uint_as_float(u.y << 16), b0.z), 0.f);
    float r3 = fmaxf(fmaf(a0.w, __uint_as_float(u.y & 0xffff0000u), b0.w), 0.f);
    float r4 = fmaxf(fmaf(a1.x, __uint_as_float(u.z << 16), b1.x), 0.f);
    float r5 = fmaxf(fmaf(a1.y, __uint_as_float(u.z & 0xffff0000u), b1.y), 0.f);
    float r6 = fmaxf(fmaf(a1.z, __uint_as_float(u.w << 16), b1.z), 0.f);
    float r7 = fmaxf(fmaf(a1.w, __uint_as_float(u.w & 0xffff0000u), b1.w), 0.f);
    uint4 o;
    o.x = pk_rne(r0, r1); o.y = pk_rne(r2, r3);
    o.z = pk_rne(r4, r5); o.w = pk_rne(r6, r7);
    ((uint4*)x1b)[t] = o;
}

// ---- K4: prop attention. S = (T@Ms)@T^T, O = P@V with V in pi-permuted key
// layout (key r -> phys 32*(r>>5) + 2*(r&15) + ((r>>4)&1)) so P writes are
// packed dwords. vt stride 328: block-9 phys slots reach 319, pad rows 300..303
// land at 312..315 (in range); phys 288..327 pre-zeroed (odd slots = dead keys).
__global__ __launch_bounds__(384, 4) void attn_mfma_kernel(const short* __restrict__ x1b,
        const short* __restrict__ msb, const short* __restrict__ wkvb,
        const int* __restrict__ obj, const int* __restrict__ bg,
        const int* __restrict__ rinds, short* __restrict__ imgb) {
    __shared__ __align__(16) short tok[304 * 40];    // tokens; reused for O in ph5
    __shared__ __align__(16) short vt[32 * 328];     // V^T, pi-permuted key cols
    __shared__ __align__(16) short pbuf[6 * 16 * 40];
    __shared__ int possh[300];
    const int b = blockIdx.x;
    const int h = b / CROP, i = b - h * CROP;
    const int tid = threadIdx.x;
    const int wave = tid >> 6, lane = tid & 63, q = lane >> 4, n = lane & 15;

    // phase 0: pos gather + zero tok pad rows + zero vt phys 288..327 (all rows)
    if (tid < 300) {
        int ri = rinds[h * HW + i * CROP + tid];
        possh[tid] = (i < 150) ? obj[ri] : bg[ri];
    }
    for (int ii = tid; ii < 80; ii += 384)
        ((unsigned*)(tok + 300 * 40))[ii] = 0;
    for (int ii = tid; ii < 640; ii += 384) {        // 32 rows x 20 dwords (slots 288..327)
        int e = ii / 20, w = ii - 20 * e;
        ((unsigned*)vt)[e * 164 + 144 + w] = 0;
    }
    __syncthreads();

    // phase 1: gather tokens (post-BN bf16)
    for (int idx = tid; idx < 1200; idx += 384) {
        int j = idx >> 2, part = idx & 3;
        *(uint4*)(tok + j * 40 + part * 8) =
            *(const uint4*)(x1b + (size_t)possh[j] * 64 + h * 32 + part * 8);
    }
    __syncthreads();

    // phase 2: Q' = T@Ms (pbuf round-trip -> aQ regs), V -> vt (pi layout)
    short* pw = pbuf + wave * 16 * 40;
    s8v aQ[4];
    {
        s8v bq0 = *(const s8v*)(msb + n * 32 + q * 8);
        s8v bq1 = *(const s8v*)(msb + (16 + n) * 32 + q * 8);
        s8v bv0 = *(const s8v*)(wkvb + (32 + n) * 32 + q * 8);
        s8v bv1 = *(const s8v*)(wkvb + (48 + n) * 32 + q * 8);
        f4v zz = {0.f, 0.f, 0.f, 0.f};
#pragma unroll
        for (int ti = 0; ti < 4; ++ti) {
            int t = wave + ti * 6;
            aQ[ti] = s8v{};
            if (t < 19) {
                s8v at = *(const s8v*)(tok + (16 * t + n) * 40 + q * 8);
                f4v qf0 = MFMA16(at, bq0, zz);
                f4v qf1 = MFMA16(at, bq1, zz);
                f4v vf0 = MFMA16(at, bv0, zz);
                f4v vf1 = MFMA16(at, bv1, zz);
#pragma unroll
                for (int r = 0; r < 4; ++r) {
                    int row = 16 * t + q * 4 + r;            // key index
                    int phys = ((row >> 5) << 5) + 2 * (row & 15) + ((row >> 4) & 1);
                    vt[n * 328 + phys]        = (short)f2bf(vf0[r]);
                    vt[(16 + n) * 328 + phys] = (short)f2bf(vf1[r]);
                    pw[(q * 4 + r) * 40 + n]      = (short)f2bf(qf0[r]);
                    pw[(q * 4 + r) * 40 + 16 + n] = (short)f2bf(qf1[r]);
                }
                asm volatile("s_waitcnt lgkmcnt(0)" ::: "memory");
                aQ[ti] = *(const s8v*)(pw + n * 40 + q * 8);
            }
        }
    }
    __syncthreads();

    // phase 4: 10 key-blocks of 32: S (B-frags from tok) -> exp -> packed P -> PV
    f4v O[4][2];
    float lsum[4][4];
#pragma unroll
    for (int ti = 0; ti < 4; ++ti) {
        O[ti][0] = f4v{0.f, 0.f, 0.f, 0.f};
        O[ti][1] = f4v{0.f, 0.f, 0.f, 0.f};
#pragma unroll
        for (int r = 0; r < 4; ++r) lsum[ti][r] = 0.f;
    }
    unsigned* pwd = (unsigned*)pw;
    f4v zz = {0.f, 0.f, 0.f, 0.f};
    for (int kb = 0; kb < 10; ++kb) {
        s8v bK0 = *(const s8v*)(tok + (32 * kb + n) * 40 + q * 8);
        s8v bK1 = (kb < 9) ? *(const s8v*)(tok + (32 * kb + 16 + n) * 40 + q * 8) : s8v{};
        s8v bV0 = *(const s8v*)(vt + n * 328 + kb * 32 + q * 8);
        s8v bV1 = *(const s8v*)(vt + (16 + n) * 328 + kb * 32 + q * 8);
#pragma unroll
        for (int ti = 0; ti < 4; ++ti) {
            int t = wave + ti * 6;
            if (t >= 19) continue;
            f4v s0 = MFMA16(aQ[ti], bK0, zz);
            if (kb < 9) {
                f4v s1 = MFMA16(aQ[ti], bK1, zz);
#pragma unroll
                for (int r = 0; r < 4; ++r) {
                    float e0 = exp2f(s0[r]);
                    float e1 = exp2f(s1[r]);
                    unsigned pk = pk_trunc(e0, e1);
                    lsum[ti][r] += __uint_as_float(pk << 16) +
                                   __uint_as_float(pk & 0xffff0000u);
                    pwd[(q * 4 + r) * 20 + n] = pk;
                }
            } else {   // keys 288..319: valid 288..299 -> mask n>=12; hi tile all pad
#pragma unroll
                for (int r = 0; r < 4; ++r) {
                    float e0 = (n < 12) ? exp2f(s0[r]) : 0.f;
                    unsigned pk = pk_trunc(e0, 0.f);
                    lsum[ti][r] += __uint_as_float(pk << 16);
                    pwd[(q * 4 + r) * 20 + n] = pk;
                }
            }
            asm volatile("s_waitcnt lgkmcnt(0)" ::: "memory");
            s8v ap = *(const s8v*)(pw + n * 40 + q * 8);
            O[ti][0] = MFMA16(ap, bV0, O[ti][0]);
            O[ti][1] = MFMA16(ap, bV1, O[ti][1]);
        }
    }
    __syncthreads();   // all tok/vt reads done; tok region becomes O buffer

    // phase 5: reduce lsum over the 16 lanes sharing each row, normalize, store O
#pragma unroll
    for (int m = 1; m < 16; m <<= 1) {
#pragma unroll
        for (int ti = 0; ti < 4; ++ti)
#pragma unroll
            for (int r = 0; r < 4; ++r)
                lsum[ti][r] += __shfl_xor(lsum[ti][r], m, 64);
    }
    short* outb = tok;   // flat [304][32] bf16
#pragma unroll
    for (int ti = 0; ti < 4; ++ti) {
        int t = wave + ti * 6;
        if (t >= 19) continue;
#pragma unroll
        for (int r = 0; r < 4; ++r) {
            float rl = 1.f / lsum[ti][r];
            int row = 16 * t + q * 4 + r;
            outb[row * 32 + n]      = (short)f2bf(O[ti][0][r] * rl);
            outb[row * 32 + 16 + n] = (short)f2bf(O[ti][1][r] * rl);
        }
    }
    __syncthreads();

    // phase 6: raw (300,32)->(32,300) reinterpret + permutation scatter (bf16)
    for (int idx = tid; idx < 9600; idx += 384) {
        int jj = idx >> 5, dd = idx & 31;
        imgb[(size_t)possh[jj] * 64 + h * 32 + dd] = outb[dd * CROP + jj];
    }
}

// ---- K5: fuse2 via MFMA, A-frags straight from bf16 buffers ----
__global__ __launch_bounds__(256, 2) void fuse2_mfma(const short* __restrict__ imgb,
        const short* __restrict__ x1b,
        const short* __restrict__ wob, const short* __restrict__ w2b,
        const float* __restrict__ bo, float* __restrict__ y2, float* __restrict__ stat) {
    __shared__ __align__(16) short xas[4][16 * 72];
    __shared__ float ytr[64 * 133];
    __shared__ float red[2][4][64];
    const int wave = threadIdx.x >> 6, lane = threadIdx.x & 63;
    const int q = lane >> 4, n = lane & 15;
    s8v Bo[2][4], B2[4][4];
#pragma unroll
    for (int kb = 0; kb < 2; ++kb)
#pragma unroll
        for (int nt = 0; nt < 4; ++nt)
            Bo[kb][nt] = *(const s8v*)(wob + (nt * 16 + n) * 64 + kb * 32 + q * 8);
#pragma unroll
    for (int kb = 0; kb < 4; ++kb)
#pragma unroll
        for (int nt = 0; nt < 4; ++nt)
            B2[kb][nt] = *(const s8v*)(w2b + (nt * 16 + n) * 128 + kb * 32 + q * 8);
    float bov[4];
#pragma unroll
    for (int nt = 0; nt < 4; ++nt) bov[nt] = bo[nt * 16 + n];

    float s1[4] = {0.f, 0.f, 0.f, 0.f}, s2[4] = {0.f, 0.f, 0.f, 0.f};
    short* xw = xas[wave];
#pragma unroll
    for (int ti = 0; ti < 2; ++ti) {
        int tile = blockIdx.x * 8 + wave * 2 + ti;
        if (tile >= 5625) continue;
        int s0 = tile * 16;
        f4v xacc[4];
#pragma unroll
        for (int nt = 0; nt < 4; ++nt) xacc[nt] = f4v{0.f, 0.f, 0.f, 0.f};
#pragma unroll
        for (int kb = 0; kb < 2; ++kb) {
            s8v A = *(const s8v*)(imgb + (size_t)(s0 + n) * 64 + kb * 32 + q * 8);
#pragma unroll
            for (int nt = 0; nt < 4; ++nt) xacc[nt] = MFMA16(A, Bo[kb][nt], xacc[nt]);
        }
#pragma unroll
        for (int nt = 0; nt < 4; ++nt)
#pragma unroll
            for (int r = 0; r < 4; ++r) {
                float v = fmaxf(xacc[nt][r] + bov[nt], 0.f);
                xw[(q * 4 + r) * 72 + nt * 16 + n] = (short)f2bf(v);
            }
        asm volatile("s_waitcnt lgkmcnt(0)" ::: "memory");
        f4v yacc[4];
#pragma unroll
        for (int nt = 0; nt < 4; ++nt) yacc[nt] = f4v{0.f, 0.f, 0.f, 0.f};
#pragma unroll
        for (int kb = 0; kb < 2; ++kb) {
            s8v Axa = *(const s8v*)(xw + n * 72 + kb * 32 + q * 8);
#pragma unroll
            for (int nt = 0; nt < 4; ++nt) yacc[nt] = MFMA16(Axa, B2[kb][nt], yacc[nt]);
        }
#pragma unroll
        for (int kb = 0; kb < 2; ++kb) {
            s8v A = *(const s8v*)(x1b + (size_t)(s0 + n) * 64 + kb * 32 + q * 8);
#pragma unroll
            for (int nt = 0; nt < 4; ++nt) yacc[nt] = MFMA16(A, B2[kb + 2][nt], yacc[nt]);
        }
        int pl = wave * 32 + ti * 16;
#pragma unroll
        for (int nt = 0; nt < 4; ++nt)
#pragma unroll
            for (int r = 0; r < 4; ++r) {
                float v = yacc[nt][r];
                s1[nt] += v; s2[nt] += v * v;
                ytr[(nt * 16 + n) * 133 + pl + q * 4 + r] = v;
            }
    }
#pragma unroll
    for (int m = 16; m < 64; m <<= 1)
#pragma unroll
        for (int nt = 0; nt < 4; ++nt) {
            s1[nt] += __shfl_xor(s1[nt], m, 64);
            s2[nt] += __shfl_xor(s2[nt], m, 64);
        }
    if (lane < 16)
#pragma unroll
        for (int nt = 0; nt < 4; ++nt) {
            red[0][wave][nt * 16 + lane] = s1[nt];
            red[1][wave][nt * 16 + lane] = s2[nt];
        }
    __syncthreads();
    int s0b = blockIdx.x * 128;
    for (int i = threadIdx.x; i < 8192; i += 256) {
        int c = i >> 7, p = i & 127;
        int s = s0b + p;
        if (s < HW) y2[(size_t)c * HW + s] = ytr[c * 133 + p];
    }
    if (threadIdx.x < 128) {
        int k = threadIdx.x >> 6, c = threadIdx.x & 63;
        atomicAdd(&stat[k * 64 + c],
                  red[k][0][c] + red[k][1][c] + red[k][2][c] + red[k][3][c]);
    }
}

// ---- K7: BN2 + relu + store, float4 ----
__global__ __launch_bounds__(256) void bn_out_kernel(const float* __restrict__ y2,
        const float* __restrict__ ab2, float* __restrict__ out) {
    int c = blockIdx.y;
    int s4 = blockIdx.x * 256 + threadIdx.x;
    if (s4 >= 22500) return;
    float a = ab2[c], b = ab2[64 + c];
    float4 v = *(const float4*)(y2 + (size_t)c * HW + s4 * 4);
    v.x = fmaxf(fmaf(a, v.x, b), 0.f);
    v.y = fmaxf(fmaf(a, v.y, b), 0.f);
    v.z = fmaxf(fmaf(a, v.z, b), 0.f);
    v.w = fmaxf(fmaf(a, v.w, b), 0.f);
    *(float4*)(out + (size_t)c * HW + s4 * 4) = v;
}

extern "C" void kernel_launch(void* const* d_in, const int* in_sizes, int n_in,
                              void* d_out, int out_size, void* d_ws, size_t ws_size,
                              hipStream_t stream) {
    const float* x   = (const float*)d_in[0];
    const float* w1  = (const float*)d_in[1];
    const float* g1  = (const float*)d_in[2];
    const float* b1  = (const float*)d_in[3];
    const float* wq  = (const float*)d_in[4];
    const float* wkv = (const float*)d_in[5];
    const float* wo  = (const float*)d_in[6];
    const float* bo  = (const float*)d_in[7];
    const float* w2  = (const float*)d_in[8];
    const float* g2  = (const float*)d_in[9];
    const float* b2  = (const float*)d_in[10];
    const int* obj   = (const int*)d_in[11];
    const int* bg    = (const int*)d_in[12];
    const int* rinds = (const int*)d_in[13];

    float* WSF  = (float*)d_ws;
    short* W1B  = (short*)d_ws;          // 16384 shorts
    short* WOB  = W1B + 16384;           // 4096
    short* W2B  = WOB + 4096;            // 8192
    short* WKVB = W2B + 8192;            // 2048
    short* MSB  = WKVB + 2048;           // 1024  (31744 shorts < 16384 floats)
    float* STAT = WSF + 16384;           // 256: sum1,sq1 | sum2,sq2
    float* AB1  = STAT + 256;            // 128
    float* AB2  = AB1 + 128;             // 128
    short* Y1B  = (short*)(WSF + 16896); // 5.76M shorts: y1 bf16 [s][64] pre-BN
    short* X1B  = Y1B + 5760000;         // 5.76M shorts: x1 bf16 [s][64] post-BN-relu
    short* IMGB = X1B + 5760000;         // 5.76M shorts: img bf16 [s][64]
    float* Y2   = WSF + 16896 + 8640000; // 5.76M floats: y2 [c][s]

    hipMemsetAsync(STAT, 0, 1024, stream);
    prep_kernel<<<16, 256, 0, stream>>>(w1, wq, wkv, wo, w2, W1B, WKVB, WOB, W2B, MSB);
    conv1_mfma<<<704, 256, 0, stream>>>(x, W1B, Y1B, STAT);
    bn_fin_kernel<<<1, 64, 0, stream>>>(STAT, g1, b1, AB1);
    bnrelu_kernel<<<2813, 256, 0, stream>>>(Y1B, AB1, X1B);
    attn_mfma_kernel<<<600, 384, 0, stream>>>(X1B, MSB, WKVB, obj, bg, rinds, IMGB);
    fuse2_mfma<<<704, 256, 0, stream>>>(IMGB, X1B, WOB, W2B, bo, Y2, STAT + 128);
    bn_fin_kernel<<<1, 64, 0, stream>>>(STAT + 128, g2, b2, AB2);
    bn_out_kernel<<<dim3(88, 64), 256, 0, stream>>>(Y2, AB2, (float*)d_out);
}

// Round 8
// 252.994 us; speedup vs baseline: 1.0730x; 1.0730x over previous
//
#include <hip/hip_runtime.h>
#include <hip/hip_bf16.h>

#define HW 90000
#define CROP 300
// scale * log2(e) = (1/sqrt(32)) * 1.4426950408889634
#define C2EXP 0.25503492f

typedef __attribute__((ext_vector_type(8))) short s8v;
typedef __attribute__((ext_vector_type(4))) float f4v;
#define MFMA16(a,b,c) __builtin_amdgcn_mfma_f32_16x16x32_bf16(a,b,c,0,0,0)

__device__ __forceinline__ unsigned short f2bf(float f) {
    unsigned int u = __float_as_uint(f);
    return (unsigned short)((u + 0x7fffu + ((u >> 16) & 1u)) >> 16);
}
__device__ __forceinline__ float bf2f(unsigned short s) {
    return __uint_as_float(((unsigned int)s) << 16);
}
// pack two fp32 -> bf16 pair by truncation (1 v_perm): low16=trunc(a), high16=trunc(b)
__device__ __forceinline__ unsigned pk_trunc(float a, float b) {
    return __builtin_amdgcn_perm(__float_as_uint(b), __float_as_uint(a), 0x07060302u);
}
__device__ __forceinline__ unsigned pk_rne(float a, float b) {
    return (unsigned)f2bf(a) | ((unsigned)f2bf(b) << 16);
}

// ---- K0: stage weights bf16 + build Ms = Wq^T @ Wk * scale * log2e (bf16, [e'][e]) ----
__global__ void prep_kernel(const float* __restrict__ w1, const float* __restrict__ wq,
                            const float* __restrict__ wkv, const float* __restrict__ wo,
                            const float* __restrict__ w2,
                            short* __restrict__ w1b, short* __restrict__ wkvb,
                            short* __restrict__ wob, short* __restrict__ w2b,
                            short* __restrict__ msb) {
    int idx = blockIdx.x * blockDim.x + threadIdx.x;
    int stride = gridDim.x * blockDim.x;
    for (int i = idx; i < 16384; i += stride) w1b[i] = (short)f2bf(w1[i]);   // [o][k] 64x256
    for (int i = idx; i < 2048; i += stride)  wkvb[i] = (short)f2bf(wkv[i]); // [o][e] 64x32
    for (int i = idx; i < 4096; i += stride)  wob[i] = (short)f2bf(wo[i]);   // [c][e] 64x64
    for (int i = idx; i < 8192; i += stride)  w2b[i] = (short)f2bf(w2[i]);   // [o][c] 64x128
    for (int i = idx; i < 1024; i += stride) {   // msb[e'][e] = C * sum_a wq[a][e]*wkv_k[a][e']
        int ep = i >> 5, e = i & 31;
        float s = 0.f;
        for (int a = 0; a < 32; ++a) s += wq[a * 32 + e] * wkv[a * 32 + ep];
        msb[i] = (short)f2bf(s * C2EXP);
    }
}

// ---- K1: conv1 via MFMA (round-5 float4 version). Wave = 64 px (4 m-tiles);
// lane n loads float4 over pixels s0+4n..+3, component mt feeds m-tile mt
// (pixel p = s0 + 4*row + mt). W1 fully staged in LDS; interleaved B cols
// c(nt,n)=(nt&1)+2n+32*(nt>>1) so bf16 stores pack channel pairs. ----
__global__ __launch_bounds__(256, 2) void conv1_mfma(const float* __restrict__ x,
        const short* __restrict__ w1b, short* __restrict__ y1b, float* __restrict__ stat) {
    __shared__ __align__(16) short lw[16384];
    __shared__ float red[2][4][64];
    const int wave = threadIdx.x >> 6, lane = threadIdx.x & 63;
    const int q = lane >> 4, n = lane & 15;
    for (int i = threadIdx.x; i < 2048; i += 256)
        ((uint4*)lw)[i] = ((const uint4*)w1b)[i];
    __syncthreads();

    const int s0 = blockIdx.x * 256 + wave * 64;
    int pbx = s0 + 4 * n;
    if (pbx > HW - 4) pbx = HW - 4;
    f4v acc[4][4];   // [mt][nt]
#pragma unroll
    for (int mt = 0; mt < 4; ++mt)
#pragma unroll
        for (int nt = 0; nt < 4; ++nt) acc[mt][nt] = f4v{0.f, 0.f, 0.f, 0.f};

    float4 cur[8], nxt[8];
#pragma unroll
    for (int j = 0; j < 8; ++j)
        cur[j] = *(const float4*)(x + (size_t)(q * 8 + j) * HW + pbx);
#pragma unroll
    for (int kb = 0; kb < 8; ++kb) {
        if (kb < 7) {
#pragma unroll
            for (int j = 0; j < 8; ++j)
                nxt[j] = *(const float4*)(x + (size_t)((kb + 1) * 32 + q * 8 + j) * HW + pbx);
        }
        s8v A[4];
#pragma unroll
        for (int mt = 0; mt < 4; ++mt) {
            union { unsigned u[4]; s8v v; } am;
#pragma unroll
            for (int w = 0; w < 4; ++w)
                am.u[w] = pk_trunc(((const float*)&cur[2 * w])[mt],
                                   ((const float*)&cur[2 * w + 1])[mt]);
            A[mt] = am.v;
        }
#pragma unroll
        for (int mt = 0; mt < 4; ++mt)
#pragma unroll
            for (int nt = 0; nt < 4; ++nt) {
                int c = (nt & 1) + 2 * n + 32 * (nt >> 1);
                s8v B = *(const s8v*)(lw + c * 256 + kb * 32 + q * 8);
                acc[mt][nt] = MFMA16(A[mt], B, acc[mt][nt]);
            }
        if (kb < 7) {
#pragma unroll
            for (int j = 0; j < 8; ++j) cur[j] = nxt[j];
        }
    }

    // store bf16 [p][64]: lane n holds channels {2n,2n+1,32+2n,33+2n}; fused stats
    float s1[4] = {0.f, 0.f, 0.f, 0.f}, s2[4] = {0.f, 0.f, 0.f, 0.f};
#pragma unroll
    for (int mt = 0; mt < 4; ++mt)
#pragma unroll
        for (int r = 0; r < 4; ++r) {
            int p = s0 + 4 * (q * 4 + r) + mt;
            if (p < HW) {
                float v0 = acc[mt][0][r], v1 = acc[mt][1][r];
                float v2 = acc[mt][2][r], v3 = acc[mt][3][r];
                *(unsigned*)(y1b + (size_t)p * 64 + 2 * n)      = pk_rne(v0, v1);
                *(unsigned*)(y1b + (size_t)p * 64 + 32 + 2 * n) = pk_rne(v2, v3);
                s1[0] += v0; s2[0] += v0 * v0;
                s1[1] += v1; s2[1] += v1 * v1;
                s1[2] += v2; s2[2] += v2 * v2;
                s1[3] += v3; s2[3] += v3 * v3;
            }
        }
#pragma unroll
    for (int m = 16; m < 64; m <<= 1)
#pragma unroll
        for (int nt = 0; nt < 4; ++nt) {
            s1[nt] += __shfl_xor(s1[nt], m, 64);
            s2[nt] += __shfl_xor(s2[nt], m, 64);
        }
    if (lane < 16)
#pragma unroll
        for (int nt = 0; nt < 4; ++nt) {
            int c = (nt & 1) + 2 * lane + 32 * (nt >> 1);
            red[0][wave][c] = s1[nt];
            red[1][wave][c] = s2[nt];
        }
    __syncthreads();
    if (threadIdx.x < 128) {
        int k = threadIdx.x >> 6, c = threadIdx.x & 63;
        atomicAdd(&stat[k * 64 + c],
                  red[k][0][c] + red[k][1][c] + red[k][2][c] + red[k][3][c]);
    }
}

// ---- BN finalize ----
__global__ void bn_fin_kernel(const float* __restrict__ stat,
        const float* __restrict__ g, const float* __restrict__ b, float* __restrict__ ab) {
    int c = threadIdx.x;
    float m = stat[c] * (1.f / HW);
    float v = stat[64 + c] * (1.f / HW) - m * m;
    float ac = g[c] * rsqrtf(v + 1e-5f);
    ab[c] = ac;
    ab[64 + c] = b[c] - m * ac;
}

// ---- K2: x1b = bf16(relu(BN1(y1b))), 16B per thread ----
__global__ __launch_bounds__(256) void bnrelu_kernel(const short* __restrict__ y1b,
        const float* __restrict__ ab1, short* __restrict__ x1b) {
    int t = blockIdx.x * 256 + threadIdx.x;
    if (t >= 720000) return;
    int cb = 8 * (t & 7);
    float4 a0 = *(const float4*)(ab1 + cb), a1 = *(const float4*)(ab1 + cb + 4);
    float4 b0 = *(const float4*)(ab1 + 64 + cb), b1 = *(const float4*)(ab1 + 64 + cb + 4);
    uint4 u = ((const uint4*)y1b)[t];
    float r0 = fmaxf(fmaf(a0.x, __uint_as_float(u.x << 16), b0.x), 0.f);
    float r1 = fmaxf(fmaf(a0.y, __uint_as_float(u.x & 0xffff0000u), b0.y), 0.f);
    float r2 = fmaxf(fmaf(a0.z, __uint_as_float(u.y << 16), b0.z), 0.f);
    float r3 = fmaxf(fmaf(a0.w, __uint_as_float(u.y & 0xffff0000u), b0.w), 0.f);
    float r4 = fmaxf(fmaf(a1.x, __uint_as_float(u.z << 16), b1.x), 0.f);
    float r5 = fmaxf(fmaf(a1.y, __uint_as_float(u.z & 0xffff0000u), b1.y), 0.f);
    float r6 = fmaxf(fmaf(a1.z, __uint_as_float(u.w << 16), b1.z), 0.f);
    float r7 = fmaxf(fmaf(a1.w, __uint_as_float(u.w & 0xffff0000u), b1.w), 0.f);
    uint4 o;
    o.x = pk_rne(r0, r1); o.y = pk_rne(r2, r3);
    o.z = pk_rne(r4, r5); o.w = pk_rne(r6, r7);
    ((uint4*)x1b)[t] = o;
}

// ---- K4: prop attention. S = (T@Ms)@T^T, O = P@V (V pi-permuted so P writes
// pack). 512 thr = 8 waves x 3 m-tiles. Per kb: batched S -> exp -> P-writes ->
// ONE lgkmcnt(0) -> P-reads -> PV (waitcnt per wave per kb: 1, not 3). ----
__global__ __launch_bounds__(512, 4) void attn_mfma_kernel(const short* __restrict__ x1b,
        const short* __restrict__ msb, const short* __restrict__ wkvb,
        const int* __restrict__ obj, const int* __restrict__ bg,
        const int* __restrict__ rinds, short* __restrict__ imgb) {
    __shared__ __align__(16) short tok[304 * 40];    // tokens; reused for O in ph5
    __shared__ __align__(16) short vt[32 * 328];     // V^T, pi-permuted key cols
    __shared__ __align__(16) short pbuf[8 * 3 * 640];
    __shared__ int possh[300];
    const int b = blockIdx.x;
    const int h = b / CROP, i = b - h * CROP;
    const int tid = threadIdx.x;
    const int wave = tid >> 6, lane = tid & 63, q = lane >> 4, n = lane & 15;
    const int nti = (wave < 3) ? 3 : 2;   // ti validity: t = wave + 8*ti < 19

    // phase 0: pos gather + zero tok pad rows + zero vt phys 288..327 (all rows)
    if (tid < 300) {
        int ri = rinds[h * HW + i * CROP + tid];
        possh[tid] = (i < 150) ? obj[ri] : bg[ri];
    }
    for (int ii = tid; ii < 80; ii += 512)
        ((unsigned*)(tok + 300 * 40))[ii] = 0;
    for (int ii = tid; ii < 640; ii += 512) {        // 32 rows x 20 dwords (slots 288..327)
        int e = ii / 20, w = ii - 20 * e;
        ((unsigned*)vt)[e * 164 + 144 + w] = 0;
    }
    __syncthreads();

    // phase 1: gather tokens (post-BN bf16)
    for (int idx = tid; idx < 1200; idx += 512) {
        int j = idx >> 2, part = idx & 3;
        *(uint4*)(tok + j * 40 + part * 8) =
            *(const uint4*)(x1b + (size_t)possh[j] * 64 + h * 32 + part * 8);
    }
    __syncthreads();

    // phase 2: Q' = T@Ms (pbuf round-trip -> aQ regs), V -> vt (pi layout)
    short* pw0 = pbuf + wave * 3 * 640;
    s8v aQ[3];
    {
        s8v bq0 = *(const s8v*)(msb + n * 32 + q * 8);
        s8v bq1 = *(const s8v*)(msb + (16 + n) * 32 + q * 8);
        s8v bv0 = *(const s8v*)(wkvb + (32 + n) * 32 + q * 8);
        s8v bv1 = *(const s8v*)(wkvb + (48 + n) * 32 + q * 8);
        f4v zz = {0.f, 0.f, 0.f, 0.f};
#pragma unroll
        for (int ti = 0; ti < 3; ++ti) {
            aQ[ti] = s8v{};
            if (ti < nti) {
                int t = wave + ti * 8;
                s8v at = *(const s8v*)(tok + (16 * t + n) * 40 + q * 8);
                f4v qf0 = MFMA16(at, bq0, zz);
                f4v qf1 = MFMA16(at, bq1, zz);
                f4v vf0 = MFMA16(at, bv0, zz);
                f4v vf1 = MFMA16(at, bv1, zz);
#pragma unroll
                for (int r = 0; r < 4; ++r) {
                    int row = 16 * t + q * 4 + r;            // key index
                    int phys = ((row >> 5) << 5) + 2 * (row & 15) + ((row >> 4) & 1);
                    vt[n * 328 + phys]        = (short)f2bf(vf0[r]);
                    vt[(16 + n) * 328 + phys] = (short)f2bf(vf1[r]);
                    pw0[(q * 4 + r) * 40 + n]      = (short)f2bf(qf0[r]);
                    pw0[(q * 4 + r) * 40 + 16 + n] = (short)f2bf(qf1[r]);
                }
                asm volatile("s_waitcnt lgkmcnt(0)" ::: "memory");
                aQ[ti] = *(const s8v*)(pw0 + n * 40 + q * 8);
            }
        }
    }
    __syncthreads();

    // phase 4: 10 key-blocks of 32, batched across the wave's 3 m-tiles
    f4v O[3][2];
    float lsum[3][4];
#pragma unroll
    for (int ti = 0; ti < 3; ++ti) {
        O[ti][0] = f4v{0.f, 0.f, 0.f, 0.f};
        O[ti][1] = f4v{0.f, 0.f, 0.f, 0.f};
#pragma unroll
        for (int r = 0; r < 4; ++r) lsum[ti][r] = 0.f;
    }
    f4v zz = {0.f, 0.f, 0.f, 0.f};
    for (int kb = 0; kb < 10; ++kb) {
        s8v bK0 = *(const s8v*)(tok + (32 * kb + n) * 40 + q * 8);
        s8v bK1 = (kb < 9) ? *(const s8v*)(tok + (32 * kb + 16 + n) * 40 + q * 8) : s8v{};
        s8v bV0 = *(const s8v*)(vt + n * 328 + kb * 32 + q * 8);
        s8v bV1 = *(const s8v*)(vt + (16 + n) * 328 + kb * 32 + q * 8);
        f4v sv[3][2];
#pragma unroll
        for (int ti = 0; ti < 3; ++ti)
            if (ti < nti) {
                sv[ti][0] = MFMA16(aQ[ti], bK0, zz);
                sv[ti][1] = MFMA16(aQ[ti], bK1, zz);
            }
#pragma unroll
        for (int ti = 0; ti < 3; ++ti)
            if (ti < nti) {
                unsigned* pwd = (unsigned*)(pbuf + (wave * 3 + ti) * 640);
                if (kb < 9) {
#pragma unroll
                    for (int r = 0; r < 4; ++r) {
                        float e0 = exp2f(sv[ti][0][r]);
                        float e1 = exp2f(sv[ti][1][r]);
                        unsigned pk = pk_trunc(e0, e1);
                        lsum[ti][r] += __uint_as_float(pk << 16) +
                                       __uint_as_float(pk & 0xffff0000u);
                        pwd[(q * 4 + r) * 20 + n] = pk;
                    }
                } else {   // keys 288..319: valid 288..299 -> mask n>=12; hi tile pad
#pragma unroll
                    for (int r = 0; r < 4; ++r) {
                        float e0 = (n < 12) ? exp2f(sv[ti][0][r]) : 0.f;
                        unsigned pk = pk_trunc(e0, 0.f);
                        lsum[ti][r] += __uint_as_float(pk << 16);
                        pwd[(q * 4 + r) * 20 + n] = pk;
                    }
                }
            }
        asm volatile("s_waitcnt lgkmcnt(0)" ::: "memory");
#pragma unroll
        for (int ti = 0; ti < 3; ++ti)
            if (ti < nti) {
                s8v ap = *(const s8v*)(pbuf + (wave * 3 + ti) * 640 + n * 40 + q * 8);
                O[ti][0] = MFMA16(ap, bV0, O[ti][0]);
                O[ti][1] = MFMA16(ap, bV1, O[ti][1]);
            }
    }
    __syncthreads();   // all tok/vt reads done; tok region becomes O buffer

    // phase 5: reduce lsum over the 16 lanes sharing each row, normalize, store O
#pragma unroll
    for (int m = 1; m < 16; m <<= 1) {
#pragma unroll
        for (int ti = 0; ti < 3; ++ti)
#pragma unroll
            for (int r = 0; r < 4; ++r)
                lsum[ti][r] += __shfl_xor(lsum[ti][r], m, 64);
    }
    short* outb = tok;   // flat [304][32] bf16
#pragma unroll
    for (int ti = 0; ti < 3; ++ti) {
        if (ti >= nti) continue;
        int t = wave + ti * 8;
#pragma unroll
        for (int r = 0; r < 4; ++r) {
            float rl = 1.f / lsum[ti][r];
            int row = 16 * t + q * 4 + r;
            outb[row * 32 + n]      = (short)f2bf(O[ti][0][r] * rl);
            outb[row * 32 + 16 + n] = (short)f2bf(O[ti][1][r] * rl);
        }
    }
    __syncthreads();

    // phase 6: raw (300,32)->(32,300) reinterpret + permutation scatter (bf16)
    for (int idx = tid; idx < 9600; idx += 512) {
        int jj = idx >> 5, dd = idx & 31;
        imgb[(size_t)possh[jj] * 64 + h * 32 + dd] = outb[dd * CROP + jj];
    }
}

// ---- K5: fuse2 via MFMA; y2 stored bf16, stats from fp32 accumulators ----
__global__ __launch_bounds__(256, 3) void fuse2_mfma(const short* __restrict__ imgb,
        const short* __restrict__ x1b,
        const short* __restrict__ wob, const short* __restrict__ w2b,
        const float* __restrict__ bo, short* __restrict__ y2b, float* __restrict__ stat) {
    __shared__ __align__(16) short xas[4][16 * 72];
    __shared__ unsigned ytrp[64 * 68];    // [c][p-pair] packed bf16
    __shared__ float red[2][4][64];
    const int wave = threadIdx.x >> 6, lane = threadIdx.x & 63;
    const int q = lane >> 4, n = lane & 15;
    s8v Bo[2][4], B2[4][4];
#pragma unroll
    for (int kb = 0; kb < 2; ++kb)
#pragma unroll
        for (int nt = 0; nt < 4; ++nt)
            Bo[kb][nt] = *(const s8v*)(wob + (nt * 16 + n) * 64 + kb * 32 + q * 8);
#pragma unroll
    for (int kb = 0; kb < 4; ++kb)
#pragma unroll
        for (int nt = 0; nt < 4; ++nt)
            B2[kb][nt] = *(const s8v*)(w2b + (nt * 16 + n) * 128 + kb * 32 + q * 8);
    float bov[4];
#pragma unroll
    for (int nt = 0; nt < 4; ++nt) bov[nt] = bo[nt * 16 + n];

    float s1[4] = {0.f, 0.f, 0.f, 0.f}, s2[4] = {0.f, 0.f, 0.f, 0.f};
    short* xw = xas[wave];
#pragma unroll
    for (int ti = 0; ti < 2; ++ti) {
        int tile = blockIdx.x * 8 + wave * 2 + ti;
        if (tile >= 5625) continue;
        int s0 = tile * 16;
        f4v xacc[4];
#pragma unroll
        for (int nt = 0; nt < 4; ++nt) xacc[nt] = f4v{0.f, 0.f, 0.f, 0.f};
#pragma unroll
        for (int kb = 0; kb < 2; ++kb) {
            s8v A = *(const s8v*)(imgb + (size_t)(s0 + n) * 64 + kb * 32 + q * 8);
#pragma unroll
            for (int nt = 0; nt < 4; ++nt) xacc[nt] = MFMA16(A, Bo[kb][nt], xacc[nt]);
        }
#pragma unroll
        for (int nt = 0; nt < 4; ++nt)
#pragma unroll
            for (int r = 0; r < 4; ++r) {
                float v = fmaxf(xacc[nt][r] + bov[nt], 0.f);
                xw[(q * 4 + r) * 72 + nt * 16 + n] = (short)f2bf(v);
            }
        asm volatile("s_waitcnt lgkmcnt(0)" ::: "memory");
        f4v yacc[4];
#pragma unroll
        for (int nt = 0; nt < 4; ++nt) yacc[nt] = f4v{0.f, 0.f, 0.f, 0.f};
#pragma unroll
        for (int kb = 0; kb < 2; ++kb) {
            s8v Axa = *(const s8v*)(xw + n * 72 + kb * 32 + q * 8);
#pragma unroll
            for (int nt = 0; nt < 4; ++nt) yacc[nt] = MFMA16(Axa, B2[kb][nt], yacc[nt]);
        }
#pragma unroll
        for (int kb = 0; kb < 2; ++kb) {
            s8v A = *(const s8v*)(x1b + (size_t)(s0 + n) * 64 + kb * 32 + q * 8);
#pragma unroll
            for (int nt = 0; nt < 4; ++nt) yacc[nt] = MFMA16(A, B2[kb + 2][nt], yacc[nt]);
        }
        // stats (fp32, exact) + packed-bf16 transpose stage
        int pl2 = wave * 16 + ti * 8;   // p-pair base within 128-px block
#pragma unroll
        for (int nt = 0; nt < 4; ++nt) {
#pragma unroll
            for (int r = 0; r < 4; ++r) {
                float v = yacc[nt][r];
                s1[nt] += v; s2[nt] += v * v;
            }
            ytrp[(nt * 16 + n) * 68 + pl2 + q * 2 + 0] = pk_rne(yacc[nt][0], yacc[nt][1]);
            ytrp[(nt * 16 + n) * 68 + pl2 + q * 2 + 1] = pk_rne(yacc[nt][2], yacc[nt][3]);
        }
    }
#pragma unroll
    for (int m = 16; m < 64; m <<= 1)
#pragma unroll
        for (int nt = 0; nt < 4; ++nt) {
            s1[nt] += __shfl_xor(s1[nt], m, 64);
            s2[nt] += __shfl_xor(s2[nt], m, 64);
        }
    if (lane < 16)
#pragma unroll
        for (int nt = 0; nt < 4; ++nt) {
            red[0][wave][nt * 16 + lane] = s1[nt];
            red[1][wave][nt * 16 + lane] = s2[nt];
        }
    __syncthreads();
    // coalesced y2 store [c][s] bf16 (dwords)
    int s0b = blockIdx.x * 128;
    int maxp2 = (HW - s0b) >> 1;   // valid p-pairs in this block (HW even)
    for (int i = threadIdx.x; i < 4096; i += 256) {
        int c = i >> 6, p2 = i & 63;
        if (p2 < maxp2)
            ((unsigned*)y2b)[c * (HW / 2) + (s0b >> 1) + p2] = ytrp[c * 68 + p2];
    }
    if (threadIdx.x < 128) {
        int k = threadIdx.x >> 6, c = threadIdx.x & 63;
        atomicAdd(&stat[k * 64 + c],
                  red[k][0][c] + red[k][1][c] + red[k][2][c] + red[k][3][c]);
    }
}

// ---- K7: BN2 + relu + store; reads bf16 y2, writes fp32 out (4 px/thread) ----
__global__ __launch_bounds__(256) void bn_out_kernel(const short* __restrict__ y2b,
        const float* __restrict__ ab2, float* __restrict__ out) {
    int c = blockIdx.y;
    int i = blockIdx.x * 256 + threadIdx.x;
    if (i >= 22500) return;
    float a = ab2[c], b = ab2[64 + c];
    uint2 u = *(const uint2*)((const unsigned*)y2b + c * (HW / 2) + 2 * i);
    float4 v;
    v.x = fmaxf(fmaf(a, __uint_as_float(u.x << 16), b), 0.f);
    v.y = fmaxf(fmaf(a, __uint_as_float(u.x & 0xffff0000u), b), 0.f);
    v.z = fmaxf(fmaf(a, __uint_as_float(u.y << 16), b), 0.f);
    v.w = fmaxf(fmaf(a, __uint_as_float(u.y & 0xffff0000u), b), 0.f);
    *(float4*)(out + (size_t)c * HW + 4 * i) = v;
}

extern "C" void kernel_launch(void* const* d_in, const int* in_sizes, int n_in,
                              void* d_out, int out_size, void* d_ws, size_t ws_size,
                              hipStream_t stream) {
    const float* x   = (const float*)d_in[0];
    const float* w1  = (const float*)d_in[1];
    const float* g1  = (const float*)d_in[2];
    const float* b1  = (const float*)d_in[3];
    const float* wq  = (const float*)d_in[4];
    const float* wkv = (const float*)d_in[5];
    const float* wo  = (const float*)d_in[6];
    const float* bo  = (const float*)d_in[7];
    const float* w2  = (const float*)d_in[8];
    const float* g2  = (const float*)d_in[9];
    const float* b2  = (const float*)d_in[10];
    const int* obj   = (const int*)d_in[11];
    const int* bg    = (const int*)d_in[12];
    const int* rinds = (const int*)d_in[13];

    float* WSF  = (float*)d_ws;
    short* W1B  = (short*)d_ws;          // 16384 shorts
    short* WOB  = W1B + 16384;           // 4096
    short* W2B  = WOB + 4096;            // 8192
    short* WKVB = W2B + 8192;            // 2048
    short* MSB  = WKVB + 2048;           // 1024  (31744 shorts < 16384 floats)
    float* STAT = WSF + 16384;           // 256: sum1,sq1 | sum2,sq2
    float* AB1  = STAT + 256;            // 128
    float* AB2  = AB1 + 128;             // 128
    short* Y1B  = (short*)(WSF + 16896); // 5.76M shorts: y1 bf16 [s][64] pre-BN
    short* X1B  = Y1B + 5760000;         // 5.76M shorts: x1 bf16 [s][64] post-BN-relu
    short* IMGB = X1B + 5760000;         // 5.76M shorts: img bf16 [s][64]
    short* Y2B  = IMGB + 5760000;        // 5.76M shorts: y2 bf16 [c][s]

    hipMemsetAsync(STAT, 0, 1024, stream);
    prep_kernel<<<16, 256, 0, stream>>>(w1, wq, wkv, wo, w2, W1B, WKVB, WOB, W2B, MSB);
    conv1_mfma<<<352, 256, 0, stream>>>(x, W1B, Y1B, STAT);
    bn_fin_kernel<<<1, 64, 0, stream>>>(STAT, g1, b1, AB1);
    bnrelu_kernel<<<2813, 256, 0, stream>>>(Y1B, AB1, X1B);
    attn_mfma_kernel<<<600, 512, 0, stream>>>(X1B, MSB, WKVB, obj, bg, rinds, IMGB);
    fuse2_mfma<<<704, 256, 0, stream>>>(IMGB, X1B, WOB, W2B, bo, Y2B, STAT + 128);
    bn_fin_kernel<<<1, 64, 0, stream>>>(STAT + 128, g2, b2, AB2);
    bn_out_kernel<<<dim3(88, 64), 256, 0, stream>>>(Y2B, AB2, (float*)d_out);
}